// Round 22
// baseline (153.205 us; speedup 1.0000x reference)
//
#include <hip/hip_runtime.h>
#include <hip/hip_bf16.h>

#define D 112
#define HEADS 28
#define HDIM 4
#define SEQ 512
#define BATCH 16
#define NTOK (BATCH*SEQ)
#define NBASES 8
#define NKNOT 12
#define KTOT (D*9)          // 1008 real K for KAN; padded to 1024
#define KPAD 1024
#define NKT (KPAD/32)       // 32 K-steps (KAN)
#define TM 16               // tokens per block in GEMM kernels
#define QJT 21              // 336/16 j-tiles in fused qkv GEMM
#define KST 12              // kpack row stride (shorts): 24B -> 6 words, 2-way banks (free)
#define VST 520             // vT row stride (bf16)
#define LOG2E 1.44269504088896f
#define ATTN_BIAS (-23.0831169f)   // -16*log2(e)

typedef __attribute__((ext_vector_type(8))) __bf16 bf16x8;
typedef __attribute__((ext_vector_type(4))) float f32x4;
typedef __attribute__((ext_vector_type(16))) float f32x16;

__device__ __forceinline__ unsigned short f2bf(float f) {
    unsigned u = __float_as_uint(f);
    unsigned r = u + 0x7FFFu + ((u >> 16) & 1u);   // RNE
    return (unsigned short)(r >> 16);
}

__device__ __forceinline__ unsigned cvt_pk_bf16(float lo, float hi) {
    unsigned r;
    asm("v_cvt_pk_bf16_f32 %0, %1, %2" : "=v"(r) : "v"(lo), "v"(hi));
    return r;
}

// ---------------- weight prep: qkv concat -> bf16 B-fragment layout ----------------
__global__ void wqkv_prep_kernel(
    const float* __restrict__ qw, const float* __restrict__ kw, const float* __restrict__ vw,
    unsigned short* __restrict__ wq)
{
    int idx = blockIdx.x * 256 + threadIdx.x;
    if (idx >= 2*4*336*32) return;
    int kk = idx & 31;
    int j  = (idx >> 5) % 336;
    int kt = ((idx >> 5) / 336) & 3;
    int l  = idx / (32*336*4);
    int i = kt*32 + kk;
    float val = 0.f;
    if (i < D) {
        int mo = j / D, jj = j % D;
        const float* src = (mo==0) ? qw : (mo==1) ? kw : vw;
        val = src[((size_t)l*D + jj)*D + i];
    }
    wq[idx] = f2bf(val);
}

// ---------------- weight prep: oproj -> bf16 B-fragment layout ----------------
__global__ void wo_prep_kernel(const float* __restrict__ ow, unsigned short* __restrict__ wo)
{
    int idx = blockIdx.x * 256 + threadIdx.x;
    if (idx >= 2*4*D*32) return;
    int kk = idx & 31;
    int j  = (idx >> 5) % D;
    int kt = ((idx >> 5) / D) & 3;
    int l  = idx / (32*D*4);
    int i = kt*32 + kk;
    float val = (i < D) ? ow[((size_t)l*D + j)*D + i] : 0.f;
    wo[idx] = f2bf(val);
}

// ---------------- fused QKV via MFMA (16 tokens/block, 8 waves, 21 j-tiles) ----------------
__global__ __launch_bounds__(512) void qkv_mfma_kernel(
    const float* __restrict__ hin, const unsigned short* __restrict__ wq,
    const float* __restrict__ qb, const float* __restrict__ kb, const float* __restrict__ vb,
    int l, float* __restrict__ q, float* __restrict__ k, float* __restrict__ v)
{
    __shared__ __align__(16) unsigned short act[TM][136];   // 16 x (128+8 pad)
    int tid = threadIdx.x;
    int t0 = blockIdx.x * TM;
    for (int e = tid; e < TM*D; e += 512) {
        int t = e / D, i = e % D;
        act[t][i] = f2bf(hin[(size_t)(t0 + t)*D + i]);
    }
    for (int e = tid; e < TM*16; e += 512) act[e/16][D + (e%16)] = 0;
    __syncthreads();

    int w = tid >> 6, lane = tid & 63, m = lane & 15, g4 = lane >> 4;
    f32x4 acc[3];
    #pragma unroll
    for (int qq = 0; qq < 3; ++qq) acc[qq] = (f32x4){0.f,0.f,0.f,0.f};
    const bf16x8* wql = (const bf16x8*)wq + (size_t)l*4*336*4;
    #pragma unroll
    for (int kt = 0; kt < 4; ++kt) {
        bf16x8 a = *(const bf16x8*)&act[m][kt*32 + g4*8];
        #pragma unroll
        for (int qq = 0; qq < 3; ++qq) {
            int jt = w + 8*qq;
            if (jt < QJT) {
                bf16x8 bf = wql[((size_t)kt*336 + jt*16 + m)*4 + g4];
                acc[qq] = __builtin_amdgcn_mfma_f32_16x16x32_bf16(a, bf, acc[qq], 0, 0, 0);
            }
        }
    }
    #pragma unroll
    for (int qq = 0; qq < 3; ++qq) {
        int jt = w + 8*qq;
        if (jt >= QJT) continue;
        int j = jt*16 + m;
        int mo = j / D, jj = j % D;
        const float* bb = (mo==0) ? qb : (mo==1) ? kb : vb;
        float bias = bb[l*D + jj];
        float scl = (mo==0) ? 0.5f*LOG2E : 1.0f;
        float* dst = (mo==0) ? q : (mo==1) ? k : v;
        int h = jj >> 2, hd = jj & 3;
        #pragma unroll
        for (int r = 0; r < 4; ++r) {
            int n = t0 + g4*4 + r;
            int bi = n >> 9, s = n & 511;
            dst[((size_t)(bi*HEADS + h)*SEQ + s)*HDIM + hd] = (acc[qq][r] + bias)*scl;
        }
    }
}

// ---------------- attention via 32x32x16 MFMA, register-only P via permlane32_swap -------
// Block = quarter (b,h): 128 queries, 4 waves x 32 queries. Scores: S^T = K.Q^T (K=16,
// mask bias in K slot 4). P redistribution S^T-layout -> PV-B-fragment is a pure
// half-exchange: v_permlane32_swap (VALU) -- no LDS, no bpermute, no selects.
// PV: O^T = V^T.P, 5th ones row -> denominators at row 4. Dual accumulators for MFMA ILP.
__global__ __launch_bounds__(256) void attn_mfma_kernel(
    const float* __restrict__ q, const float* __restrict__ k, const float* __restrict__ v,
    const int* __restrict__ mask, float* __restrict__ ctx)
{
    __shared__ __align__(16) unsigned short kpack[SEQ][KST]; // k0..3, mf, 0,0,0 (+pad) 12KB
    __shared__ __align__(16) unsigned short vT[5][VST];      // V^T + ones row          5.2KB
    int tid = threadIdx.x;
    int bh = blockIdx.x >> 2, qh = blockIdx.x & 3;
    int b = bh / HEADS, hd = bh % HEADS;

    const float4* kk = (const float4*)k + (size_t)bh*SEQ;
    const float4* vv = (const float4*)v + (size_t)bh*SEQ;
    for (int s = tid; s < SEQ; s += 256) {
        float4 kf = kk[s];
        float mf = mask[b*SEQ + s] ? ATTN_BIAS : -1e9f;
        *(uint2*)&kpack[s][0] = (uint2){cvt_pk_bf16(kf.x, kf.y), cvt_pk_bf16(kf.z, kf.w)};
        *(uint2*)&kpack[s][4] = (uint2){cvt_pk_bf16(mf, 0.f), 0u};
        float4 vf = vv[s];
        vT[0][s] = f2bf(vf.x); vT[1][s] = f2bf(vf.y);
        vT[2][s] = f2bf(vf.z); vT[3][s] = f2bf(vf.w);
        vT[4][s] = 0x3F80;   // bf16 1.0 -> denominator row
    }
    __syncthreads();

    int w = tid >> 6, lane = tid & 63;
    int m = lane & 31;          // key row (A) / d row (PV A) / query col (outputs)
    int hf = lane >> 5;         // wave half
    int q0 = qh*128 + w*32;     // this wave's query base within (b,h)

    // Q fragment: B[k][n=query m]: k slots 0..4 = q0..3, 1.0 (half 0 only)
    bf16x8 qfrag;
    {
        uint4 uq = {0,0,0,0};
        if (hf == 0) {
            float4 qf = ((const float4*)q)[(size_t)bh*SEQ + q0 + m];
            uq = (uint4){cvt_pk_bf16(qf.x, qf.y), cvt_pk_bf16(qf.z, qf.w), 0x3F80u, 0u};
        }
        qfrag = *(bf16x8*)&uq;
    }

    f32x16 oaccA = {}, oaccB = {};
    #pragma unroll 2
    for (int kb = 0; kb < SEQ; kb += 32) {
        // K fragment: A[m=key][k]: half 0 carries k0..3+mf, half 1 zero
        bf16x8 kfrag;
        {
            uint4 u = {0,0,0,0};
            if (hf == 0) {
                uint2 lo = *(const uint2*)&kpack[kb + m][0];
                uint2 hi = *(const uint2*)&kpack[kb + m][4];
                u = (uint4){lo.x, lo.y, hi.x, hi.y};
            }
            kfrag = *(bf16x8*)&u;
        }
        f32x16 sc = {};
        sc = __builtin_amdgcn_mfma_f32_32x32x16_bf16(kfrag, qfrag, sc, 0, 0, 0);
        // sc reg 4s+r = P(key kb + r + 8s + 4*hf, query q0+m)
        float p0  = __builtin_exp2f(sc[0]),  p1  = __builtin_exp2f(sc[1]);
        float p2  = __builtin_exp2f(sc[2]),  p3  = __builtin_exp2f(sc[3]);
        float p4  = __builtin_exp2f(sc[4]),  p5  = __builtin_exp2f(sc[5]);
        float p6  = __builtin_exp2f(sc[6]),  p7  = __builtin_exp2f(sc[7]);
        float p8  = __builtin_exp2f(sc[8]),  p9  = __builtin_exp2f(sc[9]);
        float p10 = __builtin_exp2f(sc[10]), p11 = __builtin_exp2f(sc[11]);
        float p12 = __builtin_exp2f(sc[12]), p13 = __builtin_exp2f(sc[13]);
        float p14 = __builtin_exp2f(sc[14]), p15 = __builtin_exp2f(sc[15]);
        unsigned c0 = cvt_pk_bf16(p0,  p1),  c1 = cvt_pk_bf16(p2,  p3);
        unsigned c2 = cvt_pk_bf16(p4,  p5),  c3 = cvt_pk_bf16(p6,  p7);
        unsigned c4 = cvt_pk_bf16(p8,  p9),  c5 = cvt_pk_bf16(p10, p11);
        unsigned c6 = cvt_pk_bf16(p12, p13), c7 = cvt_pk_bf16(p14, p15);
        // half-exchange: (word0, word2) = permlane32_swap(c0, c2), etc. (pure VALU)
        auto r02 = __builtin_amdgcn_permlane32_swap(c0, c2, false, false);
        auto r13 = __builtin_amdgcn_permlane32_swap(c1, c3, false, false);
        auto r46 = __builtin_amdgcn_permlane32_swap(c4, c6, false, false);
        auto r57 = __builtin_amdgcn_permlane32_swap(c5, c7, false, false);
        uint4 uf1 = { (unsigned)r02[0], (unsigned)r13[0], (unsigned)r02[1], (unsigned)r13[1] };
        uint4 uf2 = { (unsigned)r46[0], (unsigned)r57[0], (unsigned)r46[1], (unsigned)r57[1] };
        bf16x8 pf1 = *(bf16x8*)&uf1;
        bf16x8 pf2 = *(bf16x8*)&uf2;
        // V^T A-frags: A[m=d (rows 0..4)][k]
        uint4 z = {0,0,0,0};
        bf16x8 va1 = (m < 5) ? *(const bf16x8*)&vT[m][kb + hf*8]      : *(bf16x8*)&z;
        bf16x8 va2 = (m < 5) ? *(const bf16x8*)&vT[m][kb + 16 + hf*8] : *(bf16x8*)&z;
        oaccA = __builtin_amdgcn_mfma_f32_32x32x16_bf16(va1, pf1, oaccA, 0, 0, 0);
        oaccB = __builtin_amdgcn_mfma_f32_32x32x16_bf16(va2, pf2, oaccB, 0, 0, 0);
    }
    float o0 = oaccA[0] + oaccB[0];
    float o1 = oaccA[1] + oaccB[1];
    float o2 = oaccA[2] + oaccB[2];
    float o3 = oaccA[3] + oaccB[3];
    // denominator (row 4) lives on the other half's reg 0
    float dn = __shfl_xor(o0, 32, 64);
    float inv = __builtin_amdgcn_rcpf(dn);
    if (hf == 0) {
        int qi = q0 + m;
        float4 o = {o0*inv, o1*inv, o2*inv, o3*inv};
        ((float4*)ctx)[(size_t)(b*SEQ + qi)*HEADS + hd] = o;   // ctx in (B,S,D)
    }
}

// ---------------- Wb prep: fold (spline_w*scaler, base_w) into bf16 B-fragment layout ----
__global__ void wb_prep_kernel(
    const float* __restrict__ base_w, const float* __restrict__ spline_w,
    const float* __restrict__ scaler, unsigned short* __restrict__ wb)
{
    int idx = blockIdx.x * 256 + threadIdx.x;
    if (idx >= 2 * NKT * D * 32) return;
    int kk = idx & 31;
    int j  = (idx >> 5) % D;
    int kt = ((idx >> 5) / D) % NKT;
    int l  = idx / (32 * D * NKT);
    int k = kt * 32 + kk;
    float val = 0.f;
    if (k < KTOT) {
        int i = k / 9, b = k % 9;
        size_t ji = ((size_t)l * D + j) * D + i;
        val = (b == 8) ? base_w[ji] : spline_w[ji * NBASES + b] * scaler[ji];
    }
    wb[idx] = f2bf(val);
}

// ---------------- FUSED: oproj + res + LN1 + KAN + res + LN2 (16 tok, 8 waves) ----------
__global__ __launch_bounds__(512) void oproj_kan_ln_kernel(
    const float* __restrict__ ctx, const float* __restrict__ hin,
    const unsigned short* __restrict__ wo, const float* __restrict__ ob,
    const float* __restrict__ g1, const float* __restrict__ b1,
    const float* __restrict__ grid, const unsigned short* __restrict__ wb,
    const float* __restrict__ g2, const float* __restrict__ b2,
    int l, int gstride, float* __restrict__ hout)
{
    __shared__ __align__(16) unsigned short abuf[TM*1032];  // union: oproj stride 136 / kan stride 1032
    __shared__ float so[TM][D];
    int tid = threadIdx.x;
    int t0 = blockIdx.x * TM;
    int w = tid >> 6, lane = tid & 63, m = lane & 15, g4 = lane >> 4;
    int jw = w*16 + m;   // this wave's output column (valid when w < 7)

    // ---- 0. prefetch residuals + bias for phase 2 (before any barrier) ----
    float resv[4], obv = 0.f;
    if (w < 7) {
        obv = ob[l*D + jw];
        #pragma unroll
        for (int r = 0; r < 4; ++r)
            resv[r] = hin[(size_t)(t0 + g4*4 + r)*D + jw];
    }

    // ---- 1. stage ctx (bf16, stride 136, zero-padded cols) ----
    for (int e = tid; e < TM*136; e += 512) {
        int t = e / 136, i = e % 136;
        abuf[e] = (i < D) ? f2bf(ctx[(size_t)(t0 + t)*D + i]) : 0;
    }
    __syncthreads();

    // ---- 2. oproj MFMA + bias + residual -> so (wave w owns j-tile w) ----
    if (w < 7) {
        f32x4 acc = {0.f,0.f,0.f,0.f};
        const bf16x8* wol = (const bf16x8*)wo + (size_t)l*4*D*4;
        #pragma unroll
        for (int kt = 0; kt < 4; ++kt) {
            bf16x8 a = *(const bf16x8*)&abuf[m*136 + kt*32 + g4*8];
            bf16x8 b0 = wol[((size_t)kt*D + jw)*4 + g4];
            acc = __builtin_amdgcn_mfma_f32_16x16x32_bf16(a, b0, acc, 0, 0, 0);
        }
        #pragma unroll
        for (int r = 0; r < 4; ++r)
            so[g4*4 + r][jw] = acc[r] + obv + resv[r];
    }
    __syncthreads();

    // ---- 3. LN1 in place on so (8 waves x 2 tokens) ----
    for (int tt = 0; tt < 2; ++tt) {
        int t = w*2 + tt;
        float x0 = so[t][lane];
        float x1 = (lane + 64 < D) ? so[t][lane + 64] : 0.f;
        float s1 = x0 + x1, s2 = x0*x0 + x1*x1;
        #pragma unroll
        for (int off = 32; off; off >>= 1) { s1 += __shfl_xor(s1, off, 64); s2 += __shfl_xor(s2, off, 64); }
        float mu = s1 * (1.f/112.f);
        float var = s2 * (1.f/112.f) - mu*mu;
        float rs = rsqrtf(var + 1e-5f);
        so[t][lane] = (x0 - mu)*rs*g1[l*D + lane] + b1[l*D + lane];
        if (lane + 64 < D)
            so[t][lane+64] = (x1 - mu)*rs*g1[l*D + lane+64] + b1[l*D + lane+64];
    }
    __syncthreads();

    // ---- 4. spline basis (cardinal, direct) + silu from so -> abuf (stride 1032) ----
    for (int e = tid; e < TM * D; e += 512) {
        int tk = e / D, i = e % D;
        float xv = so[tk][i];
        float si = xv * __builtin_amdgcn_rcpf(1.f + __expf(-xv));
        const float* grp = grid + i * gstride;
        float gz = grp[0];
        float hh = grp[1] - gz;
        float u = (xv - gz) / hh;
        float fidx = floorf(u);
        int idx = (int)fidx;
        float t = u - fidx;
        float t2 = t*t, t3 = t2*t;
        const float s6 = 1.f/6.f;
        float p0 = t3 * s6;
        float p1 = (-3.f*t3 + 3.f*t2 + 3.f*t + 1.f) * s6;
        float p2 = (3.f*t3 - 6.f*t2 + 4.f) * s6;
        float om = 1.f - t;
        float p3 = om*om*om * s6;
        unsigned short* arow = &abuf[tk*1032 + i*9];
        #pragma unroll
        for (int b = 0; b < 8; ++b) arow[b] = 0;
        if (u >= 0.f && idx <= 10) {
            if (idx <= 7) arow[idx]   = f2bf(p0);
            if (idx >= 1 && idx <= 8) arow[idx-1] = f2bf(p1);
            if (idx >= 2 && idx <= 9) arow[idx-2] = f2bf(p2);
            if (idx >= 3)             arow[idx-3] = f2bf(p3);
        }
        arow[8] = f2bf(si);
    }
    for (int e = tid; e < TM * 24; e += 512)
        abuf[(e/24)*1032 + KTOT + (e%24)] = 0;
    __syncthreads();

    // ---- 5. KAN MFMA + residual (LN1 output) -> so (wave w owns j-tile w) ----
    if (w < 7) {
        f32x4 acc = {0.f,0.f,0.f,0.f};
        const bf16x8* wbl = (const bf16x8*)wb + (size_t)l * NKT * D * 4;
        #pragma unroll 4
        for (int kt = 0; kt < NKT; ++kt) {
            bf16x8 a = *(const bf16x8*)&abuf[m*1032 + kt*32 + g4*8];
            bf16x8 b0 = wbl[((size_t)kt*D + jw)*4 + g4];
            acc = __builtin_amdgcn_mfma_f32_16x16x32_bf16(a, b0, acc, 0, 0, 0);
        }
        #pragma unroll
        for (int r = 0; r < 4; ++r) {
            int t = g4*4 + r;
            so[t][jw] = acc[r] + so[t][jw];
        }
    }
    __syncthreads();

    // ---- 6. LN2 -> hout (8 waves x 2 tokens) ----
    for (int tt = 0; tt < 2; ++tt) {
        int t = w*2 + tt;
        float x0 = so[t][lane];
        float x1 = (lane + 64 < D) ? so[t][lane + 64] : 0.f;
        float s1 = x0 + x1, s2 = x0*x0 + x1*x1;
        #pragma unroll
        for (int off = 32; off; off >>= 1) { s1 += __shfl_xor(s1, off, 64); s2 += __shfl_xor(s2, off, 64); }
        float mu = s1 * (1.f/112.f);
        float var = s2 * (1.f/112.f) - mu*mu;
        float rs = rsqrtf(var + 1e-5f);
        for (int ii = lane; ii < D; ii += 64)
            hout[(size_t)(t0 + t)*D + ii] = (so[t][ii] - mu)*rs*g2[l*D + ii] + b2[l*D + ii];
    }
}

// ---------------- classifier: f32 output ----------------
__global__ __launch_bounds__(64) void cls_kernel(
    const float* __restrict__ h, const float* __restrict__ cw, const float* __restrict__ cb,
    float* __restrict__ out)
{
    int tid = threadIdx.x;
    if (tid < BATCH*2) {
        int b = tid >> 1, c = tid & 1;
        const float* hr = h + (size_t)b*SEQ*D;   // token s=0
        const float* wr = cw + c*D;
        float a = 0.f;
        for (int i = 0; i < D; ++i) a += hr[i]*wr[i];
        out[b*2 + c] = a + cb[c];
    }
}

// ---------------- ws-too-small sentinel (diagnostic) ----------------
__global__ void sentinel_kernel(float* __restrict__ out, int nel)
{
    int i = threadIdx.x;
    if (i < nel) out[i] = 1e30f;
}

extern "C" void kernel_launch(void* const* d_in, const int* in_sizes, int n_in,
                              void* d_out, int out_size, void* d_ws, size_t ws_size,
                              hipStream_t stream)
{
    const float* x      = (const float*)d_in[0];
    const int*   mask   = (const int*)  d_in[1];
    const float* grid   = (const float*)d_in[2];
    const float* qw     = (const float*)d_in[3];
    const float* qb     = (const float*)d_in[4];
    const float* kw     = (const float*)d_in[5];
    const float* kb     = (const float*)d_in[6];
    const float* vw     = (const float*)d_in[7];
    const float* vb     = (const float*)d_in[8];
    const float* ow     = (const float*)d_in[9];
    const float* ob     = (const float*)d_in[10];
    const float* ln1g   = (const float*)d_in[11];
    const float* ln1b   = (const float*)d_in[12];
    const float* ln2g   = (const float*)d_in[13];
    const float* ln2b   = (const float*)d_in[14];
    const float* base_w = (const float*)d_in[15];
    const float* spline_w = (const float*)d_in[16];
    const float* scaler = (const float*)d_in[17];
    const float* cls_w  = (const float*)d_in[18];
    const float* cls_b  = (const float*)d_in[19];

    size_t SZ   = (size_t)NTOK * D;            // 917504 floats per buffer
    size_t WBN  = (size_t)2 * NKT * D * 32;    // 229376 bf16 (kan weights)
    size_t WQN  = (size_t)2 * 4 * 336 * 32;    // 86016 bf16 (qkv weights)
    size_t WON  = (size_t)2 * 4 * D * 32;      // 28672 bf16 (oproj weights)
    size_t need = 6*SZ*sizeof(float) + (WBN + WQN + WON)*sizeof(unsigned short) + 256;
    if (ws_size < need) {
        sentinel_kernel<<<1, 64, 0, stream>>>((float*)d_out, out_size);
        return;
    }
    float* ws = (float*)d_ws;
    float* q   = ws;
    float* k   = q + SZ;
    float* v   = k + SZ;
    float* ctx = v + SZ;
    float* hA  = ctx + SZ;
    float* hB  = hA + SZ;
    unsigned short* wbuf  = (unsigned short*)(hB + SZ);
    unsigned short* wqkv  = wbuf + WBN;
    unsigned short* wobuf = wqkv + WQN;

    int gstride = (in_sizes[2] == NKNOT) ? 0 : NKNOT;

    wb_prep_kernel<<<(int)((WBN + 255)/256), 256, 0, stream>>>(base_w, spline_w, scaler, wbuf);
    wqkv_prep_kernel<<<(int)((WQN + 255)/256), 256, 0, stream>>>(qw, kw, vw, wqkv);
    wo_prep_kernel<<<(int)((WON + 255)/256), 256, 0, stream>>>(ow, wobuf);

    const float* hin = x;
    float* houts[2] = {hA, hB};
    for (int l = 0; l < 2; ++l) {
        qkv_mfma_kernel<<<NTOK/TM, 512, 0, stream>>>(hin, wqkv, qb, kb, vb, l, q, k, v);
        attn_mfma_kernel<<<BATCH*HEADS*4, 256, 0, stream>>>(q, k, v, mask, ctx);
        oproj_kan_ln_kernel<<<NTOK/TM, 512, 0, stream>>>(ctx, hin, wobuf, ob, ln1g, ln1b,
                                                         grid, wbuf, ln2g, ln2b, l, gstride, houts[l]);
        hin = houts[l];
    }
    cls_kernel<<<1, 64, 0, stream>>>(hB, cls_w, cls_b, (float*)d_out);
}